// Round 1
// baseline (500.636 us; speedup 1.0000x reference)
//
#include <hip/hip_runtime.h>
#include <math.h>

#define NROWS 32768
#define DCOLS 2048
#define EPS 1e-6f

typedef float vfloat4 __attribute__((ext_vector_type(4)));

// ---------------- Kernel 1: per-column partial sum of squares ----------------
// No atomics: each (col-half, row-block) block writes its 1024 partial sums to
// ws. Grid (2, 1024) = 2048 blocks = 8/CU (32 waves/CU) for full HBM streaming.
#define ROWS_PER_BLOCK 32
#define ROW_BLOCKS (NROWS / ROWS_PER_BLOCK)   // 1024 -> partials = 8 MiB

__global__ __launch_bounds__(256) void colsumsq_kernel(
    const float* __restrict__ x, float* __restrict__ partial)
{
    const int c  = blockIdx.x * 1024 + threadIdx.x * 4;   // column base
    const int rb = blockIdx.y;                            // row-block id

    const float* xp = x + (size_t)rb * ROWS_PER_BLOCK * DCOLS + c;

    float a0 = 0.f, a1 = 0.f, a2 = 0.f, a3 = 0.f;
    #pragma unroll 8
    for (int r = 0; r < ROWS_PER_BLOCK; ++r) {
        vfloat4 v = *(const vfloat4*)(xp + (size_t)r * DCOLS);
        a0 += v.x * v.x;
        a1 += v.y * v.y;
        a2 += v.z * v.z;
        a3 += v.w * v.w;
    }
    vfloat4 o = {a0, a1, a2, a3};
    // NT store: don't let the 8 MiB partial buffer evict x from L3
    __builtin_nontemporal_store(o, (vfloat4*)(partial + (size_t)rb * DCOLS + c));
}

// ---------------- Kernel 1b: reduce partials, precompute rsqrt ----------------
// 64 blocks x 256 threads; each block owns 32 columns, 8 row-segments of 128.
// Reads 8 MiB (L2/L3-resident), writes 2048 floats of rsqrt(u+eps).
__global__ __launch_bounds__(256) void colreduce_kernel(
    const float* __restrict__ partial, float* __restrict__ u_inv)
{
    const int col = blockIdx.x * 32 + (threadIdx.x & 31);
    const int seg = threadIdx.x >> 5;                     // 0..7

    const float* p = partial + (size_t)seg * 128 * DCOLS + col;

    float a0 = 0.f, a1 = 0.f, a2 = 0.f, a3 = 0.f;
    #pragma unroll 4
    for (int r = 0; r < 128; r += 4) {
        a0 += p[(size_t)(r + 0) * DCOLS];
        a1 += p[(size_t)(r + 1) * DCOLS];
        a2 += p[(size_t)(r + 2) * DCOLS];
        a3 += p[(size_t)(r + 3) * DCOLS];
    }
    float s = (a0 + a1) + (a2 + a3);

    __shared__ float sm[256];
    sm[threadIdx.x] = s;
    __syncthreads();
    if (threadIdx.x < 32) {
        float t = sm[threadIdx.x];
        #pragma unroll
        for (int k = 1; k < 8; ++k) t += sm[threadIdx.x + 32 * k];
        u_inv[col] = rsqrtf(t + EPS);
    }
}

// ---------------- Kernel 2: grid-stride scaled copy ----------------
// 2048 blocks x 256 threads x 32 float4s. Stripe stride (2048*256*4 floats) is
// a multiple of DCOLS, so each thread's column set is loop-invariant: load the
// 4 scale factors ONCE, then pure load-mul-NTstore streaming.
#define SCALE_BLOCKS 2048
#define SCALE_ITERS  32   // 2048*256*32 float4 = 16,777,216 = N*D/4

__global__ __launch_bounds__(256) void scale_kernel(
    const float* __restrict__ x, const float* __restrict__ u_inv,
    float* __restrict__ out)
{
    const int t = blockIdx.x * 256 + threadIdx.x;         // float4 index in stripe
    const int c = (t * 4) & (DCOLS - 1);                  // loop-invariant column

    const vfloat4 s = *(const vfloat4*)(u_inv + c);

    const vfloat4* xin  = (const vfloat4*)x + t;
    vfloat4*       xout = (vfloat4*)out + t;
    const size_t stride = (size_t)SCALE_BLOCKS * 256;     // float4 units

    #pragma unroll 8
    for (int it = 0; it < SCALE_ITERS; ++it) {
        vfloat4 v = xin[(size_t)it * stride];
        vfloat4 o = {v.x * s.x, v.y * s.y, v.z * s.z, v.w * s.w};
        // NT store: keep x resident in L3 while streaming out
        __builtin_nontemporal_store(o, &xout[(size_t)it * stride]);
    }
}

extern "C" void kernel_launch(void* const* d_in, const int* in_sizes, int n_in,
                              void* d_out, int out_size, void* d_ws, size_t ws_size,
                              hipStream_t stream) {
    const float* x = (const float*)d_in[0];
    float* out = (float*)d_out;

    float* partial = (float*)d_ws;                               // 8 MiB
    float* u_inv   = partial + (size_t)ROW_BLOCKS * DCOLS;       // 8 KiB more

    // pass 1: partial column sums of squares (no memset, no atomics)
    dim3 g1(DCOLS / 1024, ROW_BLOCKS);
    colsumsq_kernel<<<g1, 256, 0, stream>>>(x, partial);

    // pass 1b: final reduction + rsqrt precompute
    colreduce_kernel<<<DCOLS / 32, 256, 0, stream>>>(partial, u_inv);

    // pass 2: scale
    scale_kernel<<<SCALE_BLOCKS, 256, 0, stream>>>(x, u_inv, out);
}

// Round 2
// 499.578 us; speedup vs baseline: 1.0021x; 1.0021x over previous
//
#include <hip/hip_runtime.h>
#include <math.h>

#define NROWS 32768
#define DCOLS 2048
#define EPS 1e-6f

typedef float vfloat4 __attribute__((ext_vector_type(4)));

// ---------------- Kernel 1: per-column partial sum of squares ----------------
// No atomics: each (col-half, row-block) block writes its 1024 partial sums to
// ws. Grid (2, 1024) = 2048 blocks = 8/CU (32 waves/CU) for full HBM streaming.
#define ROWS_PER_BLOCK 32
#define ROW_BLOCKS (NROWS / ROWS_PER_BLOCK)   // 1024 -> partials = 8 MiB

__global__ __launch_bounds__(256) void colsumsq_kernel(
    const float* __restrict__ x, float* __restrict__ partial)
{
    const int c  = blockIdx.x * 1024 + threadIdx.x * 4;   // column base
    const int rb = blockIdx.y;                            // row-block id

    const float* xp = x + (size_t)rb * ROWS_PER_BLOCK * DCOLS + c;

    float a0 = 0.f, a1 = 0.f, a2 = 0.f, a3 = 0.f;
    #pragma unroll 16
    for (int r = 0; r < ROWS_PER_BLOCK; ++r) {
        vfloat4 v = *(const vfloat4*)(xp + (size_t)r * DCOLS);
        a0 += v.x * v.x;
        a1 += v.y * v.y;
        a2 += v.z * v.z;
        a3 += v.w * v.w;
    }
    vfloat4 o = {a0, a1, a2, a3};
    // NT store: don't let the 8 MiB partial buffer evict x from L3
    __builtin_nontemporal_store(o, (vfloat4*)(partial + (size_t)rb * DCOLS + c));
}

// ---------------- Kernel 1b: reduce partials, precompute rsqrt ----------------
// 64 blocks x 256 threads; each block owns 32 columns, 8 row-segments of 128.
// Reads 8 MiB (L2/L3-resident), writes 2048 floats of rsqrt(u+eps).
__global__ __launch_bounds__(256) void colreduce_kernel(
    const float* __restrict__ partial, float* __restrict__ u_inv)
{
    const int col = blockIdx.x * 32 + (threadIdx.x & 31);
    const int seg = threadIdx.x >> 5;                     // 0..7

    const float* p = partial + (size_t)seg * 128 * DCOLS + col;

    float a0 = 0.f, a1 = 0.f, a2 = 0.f, a3 = 0.f;
    #pragma unroll 4
    for (int r = 0; r < 128; r += 4) {
        a0 += p[(size_t)(r + 0) * DCOLS];
        a1 += p[(size_t)(r + 1) * DCOLS];
        a2 += p[(size_t)(r + 2) * DCOLS];
        a3 += p[(size_t)(r + 3) * DCOLS];
    }
    float s = (a0 + a1) + (a2 + a3);

    __shared__ float sm[256];
    sm[threadIdx.x] = s;
    __syncthreads();
    if (threadIdx.x < 32) {
        float t = sm[threadIdx.x];
        #pragma unroll
        for (int k = 1; k < 8; ++k) t += sm[threadIdx.x + 32 * k];
        u_inv[col] = rsqrtf(t + EPS);
    }
}

// ---------------- Kernel 2: grid-stride scaled copy (REVERSED sweep) ----------------
// 2048 blocks x 256 threads x 32 float4s. Stripe stride (2048*256*4 floats) is
// a multiple of DCOLS, so each thread's column set is loop-invariant: load the
// 4 scale factors ONCE, then pure load-mul-NTstore streaming.
// Sweep runs BACK-TO-FRONT: k1 read x front-to-back, so the tail of x is the
// L3-freshest — reading it first maximizes Infinity-Cache hits (x is exactly
// L3-sized, 256 MiB).
#define SCALE_BLOCKS 2048
#define SCALE_ITERS  32   // 2048*256*32 float4 = 16,777,216 = N*D/4

__global__ __launch_bounds__(256) void scale_kernel(
    const float* __restrict__ x, const float* __restrict__ u_inv,
    float* __restrict__ out)
{
    const int t = blockIdx.x * 256 + threadIdx.x;         // float4 index in stripe
    const int c = (t * 4) & (DCOLS - 1);                  // loop-invariant column

    const vfloat4 s = *(const vfloat4*)(u_inv + c);

    const vfloat4* xin  = (const vfloat4*)x + t;
    vfloat4*       xout = (vfloat4*)out + t;
    const size_t stride = (size_t)SCALE_BLOCKS * 256;     // float4 units

    #pragma unroll 8
    for (int it = SCALE_ITERS - 1; it >= 0; --it) {
        vfloat4 v = xin[(size_t)it * stride];
        vfloat4 o = {v.x * s.x, v.y * s.y, v.z * s.z, v.w * s.w};
        // NT store: keep x resident in L3 while streaming out
        __builtin_nontemporal_store(o, &xout[(size_t)it * stride]);
    }
}

extern "C" void kernel_launch(void* const* d_in, const int* in_sizes, int n_in,
                              void* d_out, int out_size, void* d_ws, size_t ws_size,
                              hipStream_t stream) {
    const float* x = (const float*)d_in[0];
    float* out = (float*)d_out;

    float* partial = (float*)d_ws;                               // 8 MiB
    float* u_inv   = partial + (size_t)ROW_BLOCKS * DCOLS;       // 8 KiB more

    // pass 1: partial column sums of squares (no memset, no atomics)
    dim3 g1(DCOLS / 1024, ROW_BLOCKS);
    colsumsq_kernel<<<g1, 256, 0, stream>>>(x, partial);

    // pass 1b: final reduction + rsqrt precompute
    colreduce_kernel<<<DCOLS / 32, 256, 0, stream>>>(partial, u_inv);

    // pass 2: scale
    scale_kernel<<<SCALE_BLOCKS, 256, 0, stream>>>(x, u_inv, out);
}

// Round 3
// 479.557 us; speedup vs baseline: 1.0440x; 1.0417x over previous
//
#include <hip/hip_runtime.h>
#include <math.h>

#define NROWS 32768
#define DCOLS 2048
#define EPS 1e-6f

typedef float vfloat4 __attribute__((ext_vector_type(4)));

// ---------------- Kernel 1: per-column sum of squares ----------------
// Block: 256 threads, each thread handles 4 consecutive columns (float4).
// Grid: (DCOLS/1024, NROWS/ROWS_PER_BLOCK). Atomic accumulate into u[DCOLS].
#define ROWS_PER_BLOCK 128

__global__ __launch_bounds__(256) void colsumsq_kernel(
    const float* __restrict__ x, float* __restrict__ u)
{
    const int c  = blockIdx.x * 1024 + threadIdx.x * 4;   // column base
    const int r0 = blockIdx.y * ROWS_PER_BLOCK;

    const vfloat4* p = (const vfloat4*)(x + (size_t)r0 * DCOLS + c);
    const size_t row_stride = DCOLS / 4;   // in float4 units

    float a0 = 0.f, a1 = 0.f, a2 = 0.f, a3 = 0.f;
    #pragma unroll 8
    for (int r = 0; r < ROWS_PER_BLOCK; ++r) {
        vfloat4 v = p[(size_t)r * row_stride];
        a0 += v.x * v.x;
        a1 += v.y * v.y;
        a2 += v.z * v.z;
        a3 += v.w * v.w;
    }
    atomicAdd(&u[c + 0], a0);
    atomicAdd(&u[c + 1], a1);
    atomicAdd(&u[c + 2], a2);
    atomicAdd(&u[c + 3], a3);
}

// ---------------- Kernel 2: scale columns by rsqrt(u + eps) ----------------
// One float4 per thread; u[] (8 KiB) lives in L1 after first touch.
// Non-temporal stores keep x resident in L3 (x is exactly L3-sized).
__global__ __launch_bounds__(256) void scale_kernel(
    const float* __restrict__ x, const float* __restrict__ u,
    float* __restrict__ out)
{
    const size_t i = ((size_t)blockIdx.x * 256 + threadIdx.x) * 4;
    const int c = (int)(i & (DCOLS - 1));   // column of element i (D divides 4-aligned)

    vfloat4 v = *(const vfloat4*)(x + i);
    vfloat4 s = *(const vfloat4*)(u + c);

    vfloat4 o;
    o.x = v.x * rsqrtf(s.x + EPS);
    o.y = v.y * rsqrtf(s.y + EPS);
    o.z = v.z * rsqrtf(s.z + EPS);
    o.w = v.w * rsqrtf(s.w + EPS);

    __builtin_nontemporal_store(o, (vfloat4*)(out + i));
}

extern "C" void kernel_launch(void* const* d_in, const int* in_sizes, int n_in,
                              void* d_out, int out_size, void* d_ws, size_t ws_size,
                              hipStream_t stream) {
    const float* x = (const float*)d_in[0];
    float* out = (float*)d_out;
    float* u = (float*)d_ws;   // DCOLS floats of scratch (8 KiB)

    // zero the accumulator (ws is re-poisoned to 0xAA before every launch)
    (void)hipMemsetAsync(u, 0, DCOLS * sizeof(float), stream);

    // pass 1: column sum of squares
    dim3 g1(DCOLS / 1024, NROWS / ROWS_PER_BLOCK);
    colsumsq_kernel<<<g1, 256, 0, stream>>>(x, u);

    // pass 2: scale
    const size_t total4 = (size_t)NROWS * DCOLS / 4;       // 16,777,216 float4s
    const int blocks2 = (int)(total4 / 256);               // 65,536 blocks
    scale_kernel<<<blocks2, 256, 0, stream>>>(x, u, out);
}